// Round 7
// baseline (593.413 us; speedup 1.0000x reference)
//
#include <hip/hip_runtime.h>
#include <stdint.h>

#define NB 8
#define LL 2048
#define SS 2048
#define DD 1024

typedef __attribute__((ext_vector_type(4))) float f32x4;
typedef __attribute__((ext_vector_type(8))) _Float16 f16x8;
typedef __attribute__((ext_vector_type(4))) unsigned short u16x4;
typedef __attribute__((ext_vector_type(8))) unsigned short u16x8;

__device__ __forceinline__ unsigned short f2h(float x) {
    return __builtin_bit_cast(unsigned short, (_Float16)x);
}

__device__ __forceinline__ void gload16(const void* g, void* l) {
    __builtin_amdgcn_global_load_lds(
        (const __attribute__((address_space(1))) unsigned int*)g,
        (__attribute__((address_space(3))) unsigned int*)l, 16, 0, 0);
}

// ---- [128][32]-u16 tile staging; read-side chunk XOR matches write-side ----
__device__ __forceinline__ void stage_u16(unsigned short* lds, const unsigned short* g,
                                          int ldk, int tid) {
#pragma unroll
    for (int i = 0; i < 2; i++) {
        int seg = i * 256 + tid;
        int r = seg >> 2, pc = seg & 3;
        int c = pc ^ ((r >> 1) & 3);
        gload16(g + (size_t)r * ldk + c * 8, lds + seg * 8);
    }
}
__device__ __forceinline__ f16x8 ldfragH(const unsigned short* lds, int row, int l4) {
    int pc = l4 ^ ((row >> 1) & 3);
    return *(const f16x8*)&lds[row * 32 + pc * 8];
}

// ---- [128][32]-f32 tile staging ----
__device__ __forceinline__ void stage_f32(float* lds, const float* g,
                                          int ldk, int tid) {
#pragma unroll
    for (int i = 0; i < 4; i++) {
        int seg = i * 256 + tid;
        int r = seg >> 3, pc = seg & 7;
        int c = pc ^ (r & 7);
        gload16(g + (size_t)r * ldk + c * 4, lds + seg * 4);
    }
}
__device__ __forceinline__ f16x8 ldfragA_f16(const float* lds, int row, int l4) {
    int p0 = (2 * l4) ^ (row & 7);
    int p1 = (2 * l4 + 1) ^ (row & 7);
    f32x4 x0 = *(const f32x4*)&lds[row * 32 + p0 * 4];
    f32x4 x1 = *(const f32x4*)&lds[row * 32 + p1 * 4];
    f16x8 r;
    r[0] = (_Float16)x0[0]; r[1] = (_Float16)x0[1];
    r[2] = (_Float16)x0[2]; r[3] = (_Float16)x0[3];
    r[4] = (_Float16)x1[0]; r[5] = (_Float16)x1[1];
    r[6] = (_Float16)x1[2]; r[7] = (_Float16)x1[3];
    return r;
}

// ---------------- W -> fp16 ----------------
__global__ __launch_bounds__(256) void k_wf16(const float* __restrict__ W,
                                              unsigned short* __restrict__ Wf) {
    int idx = blockIdx.x * 256 + threadIdx.x;
    f32x4 x = *(const f32x4*)(W + (size_t)idx * 4);
    u16x4 h;
#pragma unroll
    for (int j = 0; j < 4; j++) h[j] = f2h(x[j]);
    *(u16x4*)(Wf + (size_t)idx * 4) = h;
}

// ---------------- key -> Kh fp16 + Kl fp16 (hi/lo split) ----------------
__global__ __launch_bounds__(256) void k_prepK(const float* __restrict__ K,
                                               unsigned short* __restrict__ Kh,
                                               unsigned short* __restrict__ Kl) {
    size_t idx = (size_t)blockIdx.x * 256 + threadIdx.x;
    f32x4 x = *(const f32x4*)(K + idx * 4);
    u16x4 h, l;
#pragma unroll
    for (int j = 0; j < 4; j++) {
        _Float16 hh = (_Float16)x[j];
        h[j] = __builtin_bit_cast(unsigned short, hh);
        l[j] = __builtin_bit_cast(unsigned short, (_Float16)(x[j] - (float)hh));
    }
    *(u16x4*)(Kh + idx * 4) = h;
    *(u16x4*)(Kl + idx * 4) = l;
}

// ---------------- V transpose: [n,s,d] f32 -> [n,d,s] fp16 ----------------
__global__ __launch_bounds__(256) void k_transv(const float* __restrict__ V,
                                                unsigned short* __restrict__ Vt) {
    __shared__ float t[64][65];
    const int n = blockIdx.z;
    const int s0 = blockIdx.x * 64, d0 = blockIdx.y * 64;
    const int tid = threadIdx.x;
    const float* src = V + ((size_t)n * SS + s0) * DD + d0;
#pragma unroll
    for (int i = 0; i < 4; i++) {
        int seg = i * 256 + tid;
        int r = seg >> 4, c4 = (seg & 15) * 4;
        f32x4 x = *(const f32x4*)(src + (size_t)r * DD + c4);
        t[r][c4 + 0] = x[0]; t[r][c4 + 1] = x[1];
        t[r][c4 + 2] = x[2]; t[r][c4 + 3] = x[3];
    }
    __syncthreads();
    const int dl = tid >> 2, sc = (tid & 3) * 16;
    u16x8 o0, o1;
#pragma unroll
    for (int j = 0; j < 8; j++) o0[j] = f2h(t[sc + j][dl]);
#pragma unroll
    for (int j = 0; j < 8; j++) o1[j] = f2h(t[sc + 8 + j][dl]);
    unsigned short* dst = Vt + ((size_t)n * DD + d0 + dl) * SS + s0 + sc;
    *(u16x8*)dst = o0;
    *(u16x8*)(dst + 8) = o1;
}

// ---------------- q_proj: Q(f32 staged) x Wf16 + b -> QPh/QPl fp16 hi/lo ----------------
__global__ __launch_bounds__(256, 4) void k_qproj(const float* __restrict__ Q,
                                                  const unsigned short* __restrict__ Wf,
                                                  const float* __restrict__ bias,
                                                  unsigned short* __restrict__ QPh,
                                                  unsigned short* __restrict__ QPl) {
    __shared__ __align__(16) float Af[4096];
    __shared__ __align__(16) unsigned short Bw[4096];
    const int tid = threadIdx.x;
    const int lane = tid & 63, wv = tid >> 6;
    const int wr = wv >> 1, wc = wv & 1;
    const int l16 = lane & 15, l4 = lane >> 4;
    const size_t row0 = (size_t)blockIdx.x * 128;
    const int col0 = blockIdx.y * 128;
    const float* gA = Q + row0 * DD;
    const unsigned short* gB = Wf + (size_t)col0 * DD;

    f32x4 acc[4][4];
#pragma unroll
    for (int mi = 0; mi < 4; mi++)
#pragma unroll
        for (int ni = 0; ni < 4; ni++) acc[mi][ni] = (f32x4){0.f, 0.f, 0.f, 0.f};

    for (int kt = 0; kt < DD / 32; ++kt) {
        stage_f32(Af, gA + kt * 32, DD, tid);
        stage_u16(Bw, gB + kt * 32, DD, tid);
        __syncthreads();
        f16x8 a[4], b[4];
#pragma unroll
        for (int mi = 0; mi < 4; mi++) a[mi] = ldfragA_f16(Af, wr * 64 + mi * 16 + l16, l4);
#pragma unroll
        for (int ni = 0; ni < 4; ni++) b[ni] = ldfragH(Bw, wc * 64 + ni * 16 + l16, l4);
#pragma unroll
        for (int mi = 0; mi < 4; mi++)
#pragma unroll
            for (int ni = 0; ni < 4; ni++)
                acc[mi][ni] = __builtin_amdgcn_mfma_f32_16x16x32_f16(a[mi], b[ni], acc[mi][ni], 0, 0, 0);
        __syncthreads();
    }
#pragma unroll
    for (int mi = 0; mi < 4; mi++)
#pragma unroll
        for (int ni = 0; ni < 4; ni++) {
            int col = col0 + wc * 64 + ni * 16 + l16;
            float bv = bias[col];
#pragma unroll
            for (int r = 0; r < 4; r++) {
                size_t row = row0 + wr * 64 + mi * 16 + l4 * 4 + r;
                float v = acc[mi][ni][r] + bv;
                _Float16 h = (_Float16)v;
                _Float16 l = (_Float16)(v - (float)h);
                QPh[row * DD + col] = __builtin_bit_cast(unsigned short, h);
                QPl[row * DD + col] = __builtin_bit_cast(unsigned short, l);
            }
        }
}

// ---------------- score: 3-pass fp16 (qph*kh + qpl*kh + qph*kl), dbuf, supertile ----------------
__global__ __launch_bounds__(256, 2) void k_score3(const unsigned short* __restrict__ QPh,
                                                   const unsigned short* __restrict__ QPl,
                                                   const unsigned short* __restrict__ Kh,
                                                   const unsigned short* __restrict__ Kl,
                                                   float* __restrict__ Sc,
                                                   int band0, int lb) {
    __shared__ __align__(16) unsigned short sAh[2][4096], sAl[2][4096];
    __shared__ __align__(16) unsigned short sBh[2][4096], sBl[2][4096];
    const int tid = threadIdx.x;
    const int lane = tid & 63, wv = tid >> 6;
    const int wr = wv >> 1, wc = wv & 1;
    const int l16 = lane & 15, l4 = lane >> 4;
    const int n = blockIdx.y;
    // supertile remap: 4 K-column blocks grouped per A-panel for L2 reuse
    const int blxN = lb >> 7;
    const int grp = blxN * 4;
    const int st = blockIdx.x / grp, within = blockIdx.x % grp;
    const int tx = within % blxN;
    const int ty = st * 4 + within / blxN;

    const size_t arow0 = (size_t)n * LL + band0 + tx * 128;
    const size_t krow0 = (size_t)n * SS + ty * 128;
    const int col0 = ty * 128;

    const unsigned short* gAh = QPh + arow0 * DD;
    const unsigned short* gAl = QPl + arow0 * DD;
    const unsigned short* gBh = Kh + krow0 * DD;
    const unsigned short* gBl = Kl + krow0 * DD;

    f32x4 acc[4][4];
#pragma unroll
    for (int mi = 0; mi < 4; mi++)
#pragma unroll
        for (int ni = 0; ni < 4; ni++) acc[mi][ni] = (f32x4){0.f, 0.f, 0.f, 0.f};

    stage_u16(sAh[0], gAh, DD, tid);
    stage_u16(sAl[0], gAl, DD, tid);
    stage_u16(sBh[0], gBh, DD, tid);
    stage_u16(sBl[0], gBl, DD, tid);
    __syncthreads();

    for (int kt = 0; kt < DD / 32; ++kt) {
        int cur = kt & 1;
        if (kt + 1 < DD / 32) {
            stage_u16(sAh[cur ^ 1], gAh + (kt + 1) * 32, DD, tid);
            stage_u16(sAl[cur ^ 1], gAl + (kt + 1) * 32, DD, tid);
            stage_u16(sBh[cur ^ 1], gBh + (kt + 1) * 32, DD, tid);
            stage_u16(sBl[cur ^ 1], gBl + (kt + 1) * 32, DD, tid);
        }
        f16x8 ah[4], al[4], bh[4], bl[4];
#pragma unroll
        for (int mi = 0; mi < 4; mi++) {
            int r = wr * 64 + mi * 16 + l16;
            ah[mi] = ldfragH(sAh[cur], r, l4);
            al[mi] = ldfragH(sAl[cur], r, l4);
        }
#pragma unroll
        for (int ni = 0; ni < 4; ni++) {
            int r = wc * 64 + ni * 16 + l16;
            bh[ni] = ldfragH(sBh[cur], r, l4);
            bl[ni] = ldfragH(sBl[cur], r, l4);
        }
#pragma unroll
        for (int mi = 0; mi < 4; mi++)
#pragma unroll
            for (int ni = 0; ni < 4; ni++) {
                acc[mi][ni] = __builtin_amdgcn_mfma_f32_16x16x32_f16(ah[mi], bh[ni], acc[mi][ni], 0, 0, 0);
                acc[mi][ni] = __builtin_amdgcn_mfma_f32_16x16x32_f16(al[mi], bh[ni], acc[mi][ni], 0, 0, 0);
                acc[mi][ni] = __builtin_amdgcn_mfma_f32_16x16x32_f16(ah[mi], bl[ni], acc[mi][ni], 0, 0, 0);
            }
        __syncthreads();
    }
#pragma unroll
    for (int mi = 0; mi < 4; mi++)
#pragma unroll
        for (int ni = 0; ni < 4; ni++) {
            int col = col0 + wc * 64 + ni * 16 + l16;
#pragma unroll
            for (int r = 0; r < 4; r++) {
                int rl = tx * 128 + wr * 64 + mi * 16 + l4 * 4 + r;
                Sc[((size_t)n * lb + rl) * SS + col] = acc[mi][ni][r];
            }
        }
}

// ---------------- row softmax: Sc f32 -> P fp16 ----------------
__global__ __launch_bounds__(256) void k_softmax(const float* __restrict__ Sc,
                                                 unsigned short* __restrict__ P,
                                                 int lb, int PL, int band0p) {
    const int brow = blockIdx.x;
    const int n = brow / lb, local = brow % lb;
    const float* src = Sc + (size_t)brow * SS;
    unsigned short* dst = P + ((size_t)n * PL + band0p + local) * SS;
    const int tid = threadIdx.x;
    const int lane = tid & 63, wv = tid >> 6;
    f32x4 v[2];
    float m = -3.4e38f;
#pragma unroll
    for (int i = 0; i < 2; i++) {
        v[i] = *(const f32x4*)(src + (size_t)(tid + i * 256) * 4);
#pragma unroll
        for (int j = 0; j < 4; j++) m = fmaxf(m, v[i][j]);
    }
#pragma unroll
    for (int o = 32; o > 0; o >>= 1) m = fmaxf(m, __shfl_xor(m, o, 64));
    __shared__ float redm[4];
    __shared__ float reds[4];
    if (lane == 0) redm[wv] = m;
    __syncthreads();
    m = fmaxf(fmaxf(redm[0], redm[1]), fmaxf(redm[2], redm[3]));
    float s = 0.f;
#pragma unroll
    for (int i = 0; i < 2; i++)
#pragma unroll
        for (int j = 0; j < 4; j++) {
            v[i][j] = __expf(v[i][j] - m);
            s += v[i][j];
        }
#pragma unroll
    for (int o = 32; o > 0; o >>= 1) s += __shfl_xor(s, o, 64);
    if (lane == 0) reds[wv] = s;
    __syncthreads();
    s = reds[0] + reds[1] + reds[2] + reds[3];
    float inv = 1.0f / s;
#pragma unroll
    for (int i = 0; i < 2; i++) {
        u16x4 h;
#pragma unroll
        for (int j = 0; j < 4; j++) h[j] = f2h(v[i][j] * inv);
        *(u16x4*)(dst + (size_t)(tid + i * 256) * 4) = h;
    }
}

// ---------------- PV GEMM: P x Vt^T (fp16), f32 out (dbuf + supertile) ----------------
__global__ __launch_bounds__(256, 3) void k_pv(const unsigned short* __restrict__ P,
                                               const unsigned short* __restrict__ Vt,
                                               float* __restrict__ Out,
                                               int PL, int band0p, int band0o, int blxN) {
    __shared__ __align__(16) unsigned short Ab[2][4096], Bb[2][4096];
    const int tid = threadIdx.x;
    const int lane = tid & 63, wv = tid >> 6;
    const int wr = wv >> 1, wc = wv & 1;
    const int l16 = lane & 15, l4 = lane >> 4;
    const int n = blockIdx.y;
    const int grp = blxN * 4;
    const int st = blockIdx.x / grp, within = blockIdx.x % grp;
    const int tx = within % blxN;
    const int ty = st * 4 + within / blxN;

    const size_t arow0 = (size_t)n * PL + band0p + tx * 128;
    const size_t brow0 = (size_t)n * DD + ty * 128;
    const int col0 = ty * 128;
    const unsigned short* gA = P + arow0 * SS;
    const unsigned short* gB = Vt + brow0 * SS;

    f32x4 acc[4][4];
#pragma unroll
    for (int mi = 0; mi < 4; mi++)
#pragma unroll
        for (int ni = 0; ni < 4; ni++) acc[mi][ni] = (f32x4){0.f, 0.f, 0.f, 0.f};

    stage_u16(Ab[0], gA, SS, tid);
    stage_u16(Bb[0], gB, SS, tid);
    __syncthreads();
    int cur = 0;
    for (int kt = 0; kt < SS / 32; ++kt) {
        if (kt + 1 < SS / 32) {
            stage_u16(Ab[cur ^ 1], gA + (kt + 1) * 32, SS, tid);
            stage_u16(Bb[cur ^ 1], gB + (kt + 1) * 32, SS, tid);
        }
        f16x8 a[4], b[4];
#pragma unroll
        for (int mi = 0; mi < 4; mi++) a[mi] = ldfragH(Ab[cur], wr * 64 + mi * 16 + l16, l4);
#pragma unroll
        for (int ni = 0; ni < 4; ni++) b[ni] = ldfragH(Bb[cur], wc * 64 + ni * 16 + l16, l4);
#pragma unroll
        for (int mi = 0; mi < 4; mi++)
#pragma unroll
            for (int ni = 0; ni < 4; ni++)
                acc[mi][ni] = __builtin_amdgcn_mfma_f32_16x16x32_f16(a[mi], b[ni], acc[mi][ni], 0, 0, 0);
        __syncthreads();
        cur ^= 1;
    }
#pragma unroll
    for (int mi = 0; mi < 4; mi++)
#pragma unroll
        for (int ni = 0; ni < 4; ni++) {
            int col = col0 + wc * 64 + ni * 16 + l16;
#pragma unroll
            for (int r = 0; r < 4; r++) {
                size_t row = (size_t)n * LL + band0o + tx * 128 + wr * 64 + mi * 16 + l4 * 4 + r;
                Out[row * DD + col] = acc[mi][ni][r];
            }
        }
}

extern "C" void kernel_launch(void* const* d_in, const int* in_sizes, int n_in,
                              void* d_out, int out_size, void* d_ws, size_t ws_size,
                              hipStream_t stream) {
    const float* key   = (const float*)d_in[0];
    const float* query = (const float*)d_in[1];
    const float* value = (const float*)d_in[2];
    const float* W     = (const float*)d_in[3];
    const float* bias  = (const float*)d_in[4];
    float* out = (float*)d_out;
    char* ws = (char*)d_ws;

    const size_t szW  = (size_t)DD * DD * 2;        // 2 MiB
    const size_t szQP = (size_t)NB * LL * DD * 2;   // 32 MiB
    const size_t szK  = (size_t)NB * SS * DD * 2;   // 32 MiB
    const size_t szVt = (size_t)NB * DD * SS * 2;   // 32 MiB
    size_t off = 0;
    unsigned short* Wf  = (unsigned short*)(ws + off); off += szW;
    unsigned short* QPh = (unsigned short*)(ws + off); off += szQP;
    unsigned short* QPl = (unsigned short*)(ws + off); off += szQP;
    unsigned short* Kh  = (unsigned short*)(ws + off); off += szK;
    unsigned short* Kl  = (unsigned short*)(ws + off); off += szK;
    unsigned short* Vt  = (unsigned short*)(ws + off); off += szVt;  // 162 MiB

    const size_t szPfull = (size_t)NB * LL * SS * 2;  // 64 MiB
    auto scBytes = [](int lb) { return (size_t)NB * lb * SS * 4; };
    auto pbBytes = [](int lb) { return (size_t)NB * lb * SS * 2; };

    bool pfull = (off + scBytes(512) + szPfull) <= ws_size;
    int lb = 512;
    float* Sc;
    unsigned short* P;
    if (pfull) {
        Sc = (float*)(ws + off); off += scBytes(512);
        P  = (unsigned short*)(ws + off);
    } else {
        while (lb > 128 && off + scBytes(lb) + pbBytes(lb) > ws_size) lb >>= 1;
        Sc = (float*)(ws + off); off += scBytes(lb);
        P  = (unsigned short*)(ws + off);
    }

    k_wf16<<<dim3((DD * DD) / (4 * 256)), 256, 0, stream>>>(W, Wf);
    k_prepK<<<dim3((int)((size_t)NB * SS * DD / (4 * 256))), 256, 0, stream>>>(key, Kh, Kl);
    k_transv<<<dim3(SS / 64, DD / 64, NB), 256, 0, stream>>>(value, Vt);
    k_qproj<<<dim3((NB * LL) / 128, DD / 128), 256, 0, stream>>>(query, Wf, bias, QPh, QPl);

    const int nbands = LL / lb;
    for (int b = 0; b < nbands; b++) {
        int band0 = b * lb;
        k_score3<<<dim3((lb / 128) * (SS / 128), NB), 256, 0, stream>>>(QPh, QPl, Kh, Kl, Sc, band0, lb);
        if (pfull) {
            k_softmax<<<dim3(NB * lb), 256, 0, stream>>>(Sc, P, lb, LL, band0);
        } else {
            k_softmax<<<dim3(NB * lb), 256, 0, stream>>>(Sc, P, lb, lb, 0);
            k_pv<<<dim3((lb / 128) * (DD / 128), NB), 256, 0, stream>>>(P, Vt, out, lb, 0, band0, lb / 128);
        }
    }
    if (pfull)
        k_pv<<<dim3((LL / 128) * (DD / 128), NB), 256, 0, stream>>>(P, Vt, out, LL, 0, 0, LL / 128);
    (void)in_sizes; (void)n_in; (void)out_size;
}

// Round 8
// 555.788 us; speedup vs baseline: 1.0677x; 1.0677x over previous
//
#include <hip/hip_runtime.h>
#include <stdint.h>

#define NB 8
#define LL 2048
#define SS 2048
#define DD 1024

typedef __attribute__((ext_vector_type(4))) float f32x4;
typedef __attribute__((ext_vector_type(8))) _Float16 f16x8;
typedef __attribute__((ext_vector_type(4))) unsigned short u16x4;
typedef __attribute__((ext_vector_type(8))) unsigned short u16x8;

__device__ __forceinline__ unsigned short f2h(float x) {
    return __builtin_bit_cast(unsigned short, (_Float16)x);
}

__device__ __forceinline__ void gload16(const void* g, void* l) {
    __builtin_amdgcn_global_load_lds(
        (const __attribute__((address_space(1))) unsigned int*)g,
        (__attribute__((address_space(3))) unsigned int*)l, 16, 0, 0);
}

// ---- [128][32]-u16 tile staging; read-side chunk XOR matches write-side ----
__device__ __forceinline__ void stage_u16(unsigned short* lds, const unsigned short* g,
                                          int ldk, int tid) {
#pragma unroll
    for (int i = 0; i < 2; i++) {
        int seg = i * 256 + tid;
        int r = seg >> 2, pc = seg & 3;
        int c = pc ^ ((r >> 1) & 3);
        gload16(g + (size_t)r * ldk + c * 8, lds + seg * 8);
    }
}
__device__ __forceinline__ f16x8 ldfragH(const unsigned short* lds, int row, int l4) {
    int pc = l4 ^ ((row >> 1) & 3);
    return *(const f16x8*)&lds[row * 32 + pc * 8];
}

// ---- [128][32]-f32 tile staging ----
__device__ __forceinline__ void stage_f32(float* lds, const float* g,
                                          int ldk, int tid) {
#pragma unroll
    for (int i = 0; i < 4; i++) {
        int seg = i * 256 + tid;
        int r = seg >> 3, pc = seg & 7;
        int c = pc ^ (r & 7);
        gload16(g + (size_t)r * ldk + c * 4, lds + seg * 4);
    }
}
__device__ __forceinline__ f16x8 ldfragA_f16(const float* lds, int row, int l4) {
    int p0 = (2 * l4) ^ (row & 7);
    int p1 = (2 * l4 + 1) ^ (row & 7);
    f32x4 x0 = *(const f32x4*)&lds[row * 32 + p0 * 4];
    f32x4 x1 = *(const f32x4*)&lds[row * 32 + p1 * 4];
    f16x8 r;
    r[0] = (_Float16)x0[0]; r[1] = (_Float16)x0[1];
    r[2] = (_Float16)x0[2]; r[3] = (_Float16)x0[3];
    r[4] = (_Float16)x1[0]; r[5] = (_Float16)x1[1];
    r[6] = (_Float16)x1[2]; r[7] = (_Float16)x1[3];
    return r;
}

// ---------------- W -> fp16 ----------------
__global__ __launch_bounds__(256) void k_wf16(const float* __restrict__ W,
                                              unsigned short* __restrict__ Wf) {
    int idx = blockIdx.x * 256 + threadIdx.x;
    f32x4 x = *(const f32x4*)(W + (size_t)idx * 4);
    u16x4 h;
#pragma unroll
    for (int j = 0; j < 4; j++) h[j] = f2h(x[j]);
    *(u16x4*)(Wf + (size_t)idx * 4) = h;
}

// ---------------- key -> Kh fp16 + Kl fp16 (hi/lo split) ----------------
__global__ __launch_bounds__(256) void k_prepK(const float* __restrict__ K,
                                               unsigned short* __restrict__ Kh,
                                               unsigned short* __restrict__ Kl) {
    size_t idx = (size_t)blockIdx.x * 256 + threadIdx.x;
    f32x4 x = *(const f32x4*)(K + idx * 4);
    u16x4 h, l;
#pragma unroll
    for (int j = 0; j < 4; j++) {
        _Float16 hh = (_Float16)x[j];
        h[j] = __builtin_bit_cast(unsigned short, hh);
        l[j] = __builtin_bit_cast(unsigned short, (_Float16)(x[j] - (float)hh));
    }
    *(u16x4*)(Kh + idx * 4) = h;
    *(u16x4*)(Kl + idx * 4) = l;
}

// ---------------- V transpose: [n,s,d] f32 -> [n,d,s] fp16 ----------------
__global__ __launch_bounds__(256) void k_transv(const float* __restrict__ V,
                                                unsigned short* __restrict__ Vt) {
    __shared__ float t[64][65];
    const int n = blockIdx.z;
    const int s0 = blockIdx.x * 64, d0 = blockIdx.y * 64;
    const int tid = threadIdx.x;
    const float* src = V + ((size_t)n * SS + s0) * DD + d0;
#pragma unroll
    for (int i = 0; i < 4; i++) {
        int seg = i * 256 + tid;
        int r = seg >> 4, c4 = (seg & 15) * 4;
        f32x4 x = *(const f32x4*)(src + (size_t)r * DD + c4);
        t[r][c4 + 0] = x[0]; t[r][c4 + 1] = x[1];
        t[r][c4 + 2] = x[2]; t[r][c4 + 3] = x[3];
    }
    __syncthreads();
    const int dl = tid >> 2, sc = (tid & 3) * 16;
    u16x8 o0, o1;
#pragma unroll
    for (int j = 0; j < 8; j++) o0[j] = f2h(t[sc + j][dl]);
#pragma unroll
    for (int j = 0; j < 8; j++) o1[j] = f2h(t[sc + 8 + j][dl]);
    unsigned short* dst = Vt + ((size_t)n * DD + d0 + dl) * SS + s0 + sc;
    *(u16x8*)dst = o0;
    *(u16x8*)(dst + 8) = o1;
}

// ---------------- q_proj: Q(f32 staged) x Wf16 + b -> QPh/QPl fp16 hi/lo ----------------
__global__ __launch_bounds__(256, 4) void k_qproj(const float* __restrict__ Q,
                                                  const unsigned short* __restrict__ Wf,
                                                  const float* __restrict__ bias,
                                                  unsigned short* __restrict__ QPh,
                                                  unsigned short* __restrict__ QPl) {
    __shared__ __align__(16) float Af[4096];
    __shared__ __align__(16) unsigned short Bw[4096];
    const int tid = threadIdx.x;
    const int lane = tid & 63, wv = tid >> 6;
    const int wr = wv >> 1, wc = wv & 1;
    const int l16 = lane & 15, l4 = lane >> 4;
    const size_t row0 = (size_t)blockIdx.x * 128;
    const int col0 = blockIdx.y * 128;
    const float* gA = Q + row0 * DD;
    const unsigned short* gB = Wf + (size_t)col0 * DD;

    f32x4 acc[4][4];
#pragma unroll
    for (int mi = 0; mi < 4; mi++)
#pragma unroll
        for (int ni = 0; ni < 4; ni++) acc[mi][ni] = (f32x4){0.f, 0.f, 0.f, 0.f};

    for (int kt = 0; kt < DD / 32; ++kt) {
        stage_f32(Af, gA + kt * 32, DD, tid);
        stage_u16(Bw, gB + kt * 32, DD, tid);
        __syncthreads();
        f16x8 a[4], b[4];
#pragma unroll
        for (int mi = 0; mi < 4; mi++) a[mi] = ldfragA_f16(Af, wr * 64 + mi * 16 + l16, l4);
#pragma unroll
        for (int ni = 0; ni < 4; ni++) b[ni] = ldfragH(Bw, wc * 64 + ni * 16 + l16, l4);
#pragma unroll
        for (int mi = 0; mi < 4; mi++)
#pragma unroll
            for (int ni = 0; ni < 4; ni++)
                acc[mi][ni] = __builtin_amdgcn_mfma_f32_16x16x32_f16(a[mi], b[ni], acc[mi][ni], 0, 0, 0);
        __syncthreads();
    }
#pragma unroll
    for (int mi = 0; mi < 4; mi++)
#pragma unroll
        for (int ni = 0; ni < 4; ni++) {
            int col = col0 + wc * 64 + ni * 16 + l16;
            float bv = bias[col];
#pragma unroll
            for (int r = 0; r < 4; r++) {
                size_t row = row0 + wr * 64 + mi * 16 + l4 * 4 + r;
                float v = acc[mi][ni][r] + bv;
                _Float16 h = (_Float16)v;
                _Float16 l = (_Float16)(v - (float)h);
                QPh[row * DD + col] = __builtin_bit_cast(unsigned short, h);
                QPl[row * DD + col] = __builtin_bit_cast(unsigned short, l);
            }
        }
}

// ---------------- score: 3-pass fp16, single-buffer high-occupancy, supertile ----------------
__global__ __launch_bounds__(256, 4) void k_score3(const unsigned short* __restrict__ QPh,
                                                   const unsigned short* __restrict__ QPl,
                                                   const unsigned short* __restrict__ Kh,
                                                   const unsigned short* __restrict__ Kl,
                                                   float* __restrict__ Sc,
                                                   int band0, int lb) {
    __shared__ __align__(16) unsigned short sAh[4096], sAl[4096];
    __shared__ __align__(16) unsigned short sBh[4096], sBl[4096];
    const int tid = threadIdx.x;
    const int lane = tid & 63, wv = tid >> 6;
    const int wr = wv >> 1, wc = wv & 1;
    const int l16 = lane & 15, l4 = lane >> 4;
    const int n = blockIdx.y;
    // supertile remap: 4 K-column blocks grouped per A-panel for L2 reuse
    const int blxN = lb >> 7;
    const int grp = blxN * 4;
    const int st = blockIdx.x / grp, within = blockIdx.x % grp;
    const int tx = within % blxN;
    const int ty = st * 4 + within / blxN;

    const size_t arow0 = (size_t)n * LL + band0 + tx * 128;
    const size_t krow0 = (size_t)n * SS + ty * 128;
    const int col0 = ty * 128;

    const unsigned short* gAh = QPh + arow0 * DD;
    const unsigned short* gAl = QPl + arow0 * DD;
    const unsigned short* gBh = Kh + krow0 * DD;
    const unsigned short* gBl = Kl + krow0 * DD;

    f32x4 acc[4][4];
#pragma unroll
    for (int mi = 0; mi < 4; mi++)
#pragma unroll
        for (int ni = 0; ni < 4; ni++) acc[mi][ni] = (f32x4){0.f, 0.f, 0.f, 0.f};

    for (int kt = 0; kt < DD / 32; ++kt) {
        stage_u16(sAh, gAh + kt * 32, DD, tid);
        stage_u16(sAl, gAl + kt * 32, DD, tid);
        stage_u16(sBh, gBh + kt * 32, DD, tid);
        stage_u16(sBl, gBl + kt * 32, DD, tid);
        __syncthreads();
        f16x8 ah[4], al[4], bh[4], bl[4];
#pragma unroll
        for (int mi = 0; mi < 4; mi++) {
            int r = wr * 64 + mi * 16 + l16;
            ah[mi] = ldfragH(sAh, r, l4);
            al[mi] = ldfragH(sAl, r, l4);
        }
#pragma unroll
        for (int ni = 0; ni < 4; ni++) {
            int r = wc * 64 + ni * 16 + l16;
            bh[ni] = ldfragH(sBh, r, l4);
            bl[ni] = ldfragH(sBl, r, l4);
        }
#pragma unroll
        for (int mi = 0; mi < 4; mi++)
#pragma unroll
            for (int ni = 0; ni < 4; ni++) {
                acc[mi][ni] = __builtin_amdgcn_mfma_f32_16x16x32_f16(ah[mi], bh[ni], acc[mi][ni], 0, 0, 0);
                acc[mi][ni] = __builtin_amdgcn_mfma_f32_16x16x32_f16(al[mi], bh[ni], acc[mi][ni], 0, 0, 0);
                acc[mi][ni] = __builtin_amdgcn_mfma_f32_16x16x32_f16(ah[mi], bl[ni], acc[mi][ni], 0, 0, 0);
            }
        __syncthreads();
    }
#pragma unroll
    for (int mi = 0; mi < 4; mi++)
#pragma unroll
        for (int ni = 0; ni < 4; ni++) {
            int col = col0 + wc * 64 + ni * 16 + l16;
#pragma unroll
            for (int r = 0; r < 4; r++) {
                int rl = tx * 128 + wr * 64 + mi * 16 + l4 * 4 + r;
                Sc[((size_t)n * lb + rl) * SS + col] = acc[mi][ni][r];
            }
        }
}

// ---------------- row softmax: Sc f32 -> P fp16 ----------------
__global__ __launch_bounds__(256) void k_softmax(const float* __restrict__ Sc,
                                                 unsigned short* __restrict__ P,
                                                 int lb, int PL, int band0p) {
    const int brow = blockIdx.x;
    const int n = brow / lb, local = brow % lb;
    const float* src = Sc + (size_t)brow * SS;
    unsigned short* dst = P + ((size_t)n * PL + band0p + local) * SS;
    const int tid = threadIdx.x;
    const int lane = tid & 63, wv = tid >> 6;
    f32x4 v[2];
    float m = -3.4e38f;
#pragma unroll
    for (int i = 0; i < 2; i++) {
        v[i] = *(const f32x4*)(src + (size_t)(tid + i * 256) * 4);
#pragma unroll
        for (int j = 0; j < 4; j++) m = fmaxf(m, v[i][j]);
    }
#pragma unroll
    for (int o = 32; o > 0; o >>= 1) m = fmaxf(m, __shfl_xor(m, o, 64));
    __shared__ float redm[4];
    __shared__ float reds[4];
    if (lane == 0) redm[wv] = m;
    __syncthreads();
    m = fmaxf(fmaxf(redm[0], redm[1]), fmaxf(redm[2], redm[3]));
    float s = 0.f;
#pragma unroll
    for (int i = 0; i < 2; i++)
#pragma unroll
        for (int j = 0; j < 4; j++) {
            v[i][j] = __expf(v[i][j] - m);
            s += v[i][j];
        }
#pragma unroll
    for (int o = 32; o > 0; o >>= 1) s += __shfl_xor(s, o, 64);
    if (lane == 0) reds[wv] = s;
    __syncthreads();
    s = reds[0] + reds[1] + reds[2] + reds[3];
    float inv = 1.0f / s;
#pragma unroll
    for (int i = 0; i < 2; i++) {
        u16x4 h;
#pragma unroll
        for (int j = 0; j < 4; j++) h[j] = f2h(v[i][j] * inv);
        *(u16x4*)(dst + (size_t)(tid + i * 256) * 4) = h;
    }
}

// ---------------- PV GEMM: P x Vt^T (fp16), f32 out (single-buffer + supertile) ----------------
__global__ __launch_bounds__(256, 4) void k_pv(const unsigned short* __restrict__ P,
                                               const unsigned short* __restrict__ Vt,
                                               float* __restrict__ Out,
                                               int PL, int band0p, int band0o, int blxN) {
    __shared__ __align__(16) unsigned short Ab[4096], Bb[4096];
    const int tid = threadIdx.x;
    const int lane = tid & 63, wv = tid >> 6;
    const int wr = wv >> 1, wc = wv & 1;
    const int l16 = lane & 15, l4 = lane >> 4;
    const int n = blockIdx.y;
    const int grp = blxN * 4;
    const int st = blockIdx.x / grp, within = blockIdx.x % grp;
    const int tx = within % blxN;
    const int ty = st * 4 + within / blxN;

    const size_t arow0 = (size_t)n * PL + band0p + tx * 128;
    const size_t brow0 = (size_t)n * DD + ty * 128;
    const int col0 = ty * 128;
    const unsigned short* gA = P + arow0 * SS;
    const unsigned short* gB = Vt + brow0 * SS;

    f32x4 acc[4][4];
#pragma unroll
    for (int mi = 0; mi < 4; mi++)
#pragma unroll
        for (int ni = 0; ni < 4; ni++) acc[mi][ni] = (f32x4){0.f, 0.f, 0.f, 0.f};

    for (int kt = 0; kt < SS / 32; ++kt) {
        stage_u16(Ab, gA + kt * 32, SS, tid);
        stage_u16(Bb, gB + kt * 32, SS, tid);
        __syncthreads();
        f16x8 a[4], b[4];
#pragma unroll
        for (int mi = 0; mi < 4; mi++) a[mi] = ldfragH(Ab, wr * 64 + mi * 16 + l16, l4);
#pragma unroll
        for (int ni = 0; ni < 4; ni++) b[ni] = ldfragH(Bb, wc * 64 + ni * 16 + l16, l4);
#pragma unroll
        for (int mi = 0; mi < 4; mi++)
#pragma unroll
            for (int ni = 0; ni < 4; ni++)
                acc[mi][ni] = __builtin_amdgcn_mfma_f32_16x16x32_f16(a[mi], b[ni], acc[mi][ni], 0, 0, 0);
        __syncthreads();
    }
#pragma unroll
    for (int mi = 0; mi < 4; mi++)
#pragma unroll
        for (int ni = 0; ni < 4; ni++) {
            int col = col0 + wc * 64 + ni * 16 + l16;
#pragma unroll
            for (int r = 0; r < 4; r++) {
                size_t row = (size_t)n * LL + band0o + tx * 128 + wr * 64 + mi * 16 + l4 * 4 + r;
                Out[row * DD + col] = acc[mi][ni][r];
            }
        }
}

extern "C" void kernel_launch(void* const* d_in, const int* in_sizes, int n_in,
                              void* d_out, int out_size, void* d_ws, size_t ws_size,
                              hipStream_t stream) {
    const float* key   = (const float*)d_in[0];
    const float* query = (const float*)d_in[1];
    const float* value = (const float*)d_in[2];
    const float* W     = (const float*)d_in[3];
    const float* bias  = (const float*)d_in[4];
    float* out = (float*)d_out;
    char* ws = (char*)d_ws;

    const size_t szW  = (size_t)DD * DD * 2;        // 2 MiB
    const size_t szQP = (size_t)NB * LL * DD * 2;   // 32 MiB
    const size_t szK  = (size_t)NB * SS * DD * 2;   // 32 MiB
    const size_t szVt = (size_t)NB * DD * SS * 2;   // 32 MiB
    size_t off = 0;
    unsigned short* Wf  = (unsigned short*)(ws + off); off += szW;
    unsigned short* QPh = (unsigned short*)(ws + off); off += szQP;
    unsigned short* QPl = (unsigned short*)(ws + off); off += szQP;
    unsigned short* Kh  = (unsigned short*)(ws + off); off += szK;
    unsigned short* Kl  = (unsigned short*)(ws + off); off += szK;
    unsigned short* Vt  = (unsigned short*)(ws + off); off += szVt;  // 162 MiB

    const size_t szPfull = (size_t)NB * LL * SS * 2;  // 64 MiB
    auto scBytes = [](int lb) { return (size_t)NB * lb * SS * 4; };
    auto pbBytes = [](int lb) { return (size_t)NB * lb * SS * 2; };

    bool pfull = (off + scBytes(512) + szPfull) <= ws_size;
    int lb = 512;
    float* Sc;
    unsigned short* P;
    if (pfull) {
        Sc = (float*)(ws + off); off += scBytes(512);
        P  = (unsigned short*)(ws + off);
    } else {
        while (lb > 128 && off + scBytes(lb) + pbBytes(lb) > ws_size) lb >>= 1;
        Sc = (float*)(ws + off); off += scBytes(lb);
        P  = (unsigned short*)(ws + off);
    }

    k_wf16<<<dim3((DD * DD) / (4 * 256)), 256, 0, stream>>>(W, Wf);
    k_prepK<<<dim3((int)((size_t)NB * SS * DD / (4 * 256))), 256, 0, stream>>>(key, Kh, Kl);
    k_transv<<<dim3(SS / 64, DD / 64, NB), 256, 0, stream>>>(value, Vt);
    k_qproj<<<dim3((NB * LL) / 128, DD / 128), 256, 0, stream>>>(query, Wf, bias, QPh, QPl);

    const int nbands = LL / lb;
    for (int b = 0; b < nbands; b++) {
        int band0 = b * lb;
        k_score3<<<dim3((lb / 128) * (SS / 128), NB), 256, 0, stream>>>(QPh, QPl, Kh, Kl, Sc, band0, lb);
        if (pfull) {
            k_softmax<<<dim3(NB * lb), 256, 0, stream>>>(Sc, P, lb, LL, band0);
        } else {
            k_softmax<<<dim3(NB * lb), 256, 0, stream>>>(Sc, P, lb, lb, 0);
            k_pv<<<dim3((lb / 128) * (DD / 128), NB), 256, 0, stream>>>(P, Vt, out, lb, 0, band0, lb / 128);
        }
    }
    if (pfull)
        k_pv<<<dim3((LL / 128) * (DD / 128), NB), 256, 0, stream>>>(P, Vt, out, LL, 0, 0, LL / 128);
    (void)in_sizes; (void)n_in; (void)out_size;
}